// Round 1
// baseline (1106.300 us; speedup 1.0000x reference)
//
#include <hip/hip_runtime.h>

// Problem constants
#define BB 32
#define CC 32
#define VV 2048
#define LL 12
#define NCOL 12288      // B*C*L columns of the mega GEMM
#define MMEGA 8192      // 4*V rows (k-blocks: A0, A0^2, A1, A1^2)

typedef __attribute__((ext_vector_type(8))) short bf16x8;
typedef __attribute__((ext_vector_type(4))) float f32x4;

__device__ __forceinline__ unsigned short f2b(float f) {
    union { float f; unsigned u; } v; v.f = f;
    unsigned u = v.u;
    unsigned r = (u + 0x7fffu + ((u >> 16) & 1u)) >> 16;
    return (unsigned short)r;
}
__device__ __forceinline__ float b2f(unsigned short h) {
    union { unsigned u; float f; } v; v.u = ((unsigned)h) << 16;
    return v.f;
}

#define GLD16(g, l) __builtin_amdgcn_global_load_lds( \
    (const __attribute__((address_space(1))) void*)(g), \
    (__attribute__((address_space(3))) void*)(l), 16, 0, 0)

// ---------------------------------------------------------------------------
// Kernel 1: fp32 -> bf16 elementwise convert (supports natural layout)
__global__ void k_convert_bf16(const float* __restrict__ src,
                               unsigned short* __restrict__ dst) {
    size_t i = (size_t)(blockIdx.x * blockDim.x + threadIdx.x) * 4;
    float4 v = *(const float4*)(src + i);
    unsigned short o0 = f2b(v.x), o1 = f2b(v.y), o2 = f2b(v.z), o3 = f2b(v.w);
    ushort4 o; o.x = o0; o.y = o1; o.z = o2; o.w = o3;
    *(ushort4*)(dst + i) = o;
}

// ---------------------------------------------------------------------------
// Kernel 2: transpose-convert A_s (fp32 [V][V]) into Gt block rows:
//   Gt[(2s)*V + w][v] = A_s[v][w]   (bf16)
__global__ void k_transpose_A(const float* __restrict__ A,
                              unsigned short* __restrict__ Gt) {
    __shared__ float t[32][33];
    const int s = blockIdx.z;
    const float* As = A + (size_t)s * VV * VV;
    const int w0 = blockIdx.x * 32, v0 = blockIdx.y * 32;
    const int tid = threadIdx.x;
    const int cc = tid & 31;
#pragma unroll
    for (int i = 0; i < 4; i++) {
        int rr = (tid >> 5) + i * 8;
        t[rr][cc] = As[(size_t)(v0 + rr) * VV + w0 + cc];
    }
    __syncthreads();
    unsigned short* G = Gt + (size_t)(2 * s) * VV * VV;
#pragma unroll
    for (int i = 0; i < 4; i++) {
        int rr = (tid >> 5) + i * 8;
        G[(size_t)(w0 + rr) * VV + v0 + cc] = f2b(t[cc][rr]);
    }
}

// ---------------------------------------------------------------------------
// Kernel 3: transpose x [B][C][V][L] fp32 -> Xb [(b*32+c)*12 + l][v] bf16
__global__ void k_transpose_x(const float* __restrict__ x,
                              unsigned short* __restrict__ Xb) {
    __shared__ float t[128 * 13];
    const int bc = blockIdx.y;
    const int v0 = blockIdx.x * 128;
    const float* xs = x + (size_t)bc * VV * LL + (size_t)v0 * LL;
    const int tid = threadIdx.x;  // 256
#pragma unroll
    for (int i = 0; i < 6; i++) {
        int e = tid + i * 256;            // 0..1535 = col*12+row
        int col = e / 12, row = e - col * 12;
        t[col * 13 + row] = xs[e];
    }
    __syncthreads();
    unsigned short* X = Xb + (size_t)bc * LL * VV + v0;
#pragma unroll
    for (int i = 0; i < 6; i++) {
        int e = tid + i * 256;
        int row = e >> 7, col = e & 127;  // row<12, col<128
        X[(size_t)row * VV + col] = f2b(t[col * 13 + row]);
    }
}

// ---------------------------------------------------------------------------
// Kernel 4: bf16 MFMA GEMM, C[m,n] = sum_k Aop[m,k] * Bop[n,k]  (B given K-contiguous)
// 128x128 tile, BK=32, 4 waves (2x2 of 64x64), m97-style structure.
// Grid: x = N/128, y = M/128.  lda = ldb = K.  C written bf16 with ldc.
__global__ __launch_bounds__(256) void k_gemm_bt(const unsigned short* __restrict__ Ag,
                                                 const unsigned short* __restrict__ Bg,
                                                 unsigned short* __restrict__ Cg,
                                                 int K, int ldc) {
    __shared__ unsigned short As[128 * 32];
    __shared__ unsigned short Bs[128 * 32];
    const int tid = threadIdx.x;
    const int lane = tid & 63;
    const int wid = tid >> 6;
    const int m0 = blockIdx.y * 128;
    const int n0 = blockIdx.x * 128;
    const int wr = wid >> 1, wc = wid & 1;

    f32x4 acc[4][4];
#pragma unroll
    for (int i = 0; i < 4; i++)
#pragma unroll
        for (int j = 0; j < 4; j++) { f32x4 z = {0.f, 0.f, 0.f, 0.f}; acc[i][j] = z; }

    const int srow = lane >> 2;           // 0..15
    const int scol = (lane & 3) * 8;      // k-element offset (16B)
    const unsigned short* gA = Ag + (size_t)(m0 + wid * 32 + srow) * K + scol;
    const unsigned short* gB = Bg + (size_t)(n0 + wid * 32 + srow) * K + scol;
    unsigned short* lA = As + (wid * 32) * 32;
    unsigned short* lB = Bs + (wid * 32) * 32;

    const int fr = lane & 15;
    const int fk = (lane >> 4) * 8;

    for (int k0 = 0; k0 < K; k0 += 32) {
        GLD16(gA + k0,                 lA);
        GLD16(gA + (size_t)16 * K + k0, lA + 16 * 32);
        GLD16(gB + k0,                 lB);
        GLD16(gB + (size_t)16 * K + k0, lB + 16 * 32);
        __syncthreads();   // compiler drains vmcnt(0) before barrier -> LDS ready

        bf16x8 fa[4], fb[4];
#pragma unroll
        for (int i = 0; i < 4; i++)
            fa[i] = *(const bf16x8*)&As[(wr * 64 + i * 16 + fr) * 32 + fk];
#pragma unroll
        for (int j = 0; j < 4; j++)
            fb[j] = *(const bf16x8*)&Bs[(wc * 64 + j * 16 + fr) * 32 + fk];
#pragma unroll
        for (int i = 0; i < 4; i++)
#pragma unroll
            for (int j = 0; j < 4; j++)
                acc[i][j] = __builtin_amdgcn_mfma_f32_16x16x32_bf16(fa[i], fb[j], acc[i][j], 0, 0, 0);
        __syncthreads();   // protect LDS before next stage overwrites
    }

    const int er = (lane >> 4) * 4;
    const int ec = lane & 15;
#pragma unroll
    for (int i = 0; i < 4; i++)
#pragma unroll
        for (int j = 0; j < 4; j++) {
            int row = m0 + wr * 64 + i * 16 + er;
            int col = n0 + wc * 64 + j * 16 + ec;
#pragma unroll
            for (int r = 0; r < 4; r++)
                Cg[(size_t)(row + r) * ldc + col] = f2b(acc[i][j][r]);
        }
}

// ---------------------------------------------------------------------------
// Kernel 5: epilogue channel mix (fp32):
//   y[b,o,w,l] = bias[o] + sum_c W[o][c]*x[b,c,w,l]
//              + sum_{k,c} W[o][(k+1)*32+c] * U[k*V + w][(b*32+c)*12 + l]
// Block: 192 threads = (w in 16) x (l in 12). Grid: (V/16, B).
__global__ __launch_bounds__(192) void k_epilogue(const float* __restrict__ x,
                                                  const unsigned short* __restrict__ U,
                                                  const float* __restrict__ W,
                                                  const float* __restrict__ bias,
                                                  float* __restrict__ y) {
    __shared__ float xs[32][192];            // 24 KB
    __shared__ unsigned short us[64][392];   // padded rows (784B) ~50 KB
    const int b = blockIdx.y;
    const int w0 = blockIdx.x * 16;
    const int tid = threadIdx.x;  // 0..191

    const float* xp = x + ((size_t)(b * 32) * VV + w0) * LL;
#pragma unroll 4
    for (int c = 0; c < 32; c++)
        xs[c][tid] = xp[(size_t)c * (VV * LL) + tid];

    for (int kk = 0; kk < 64; kk++) {
        int krow = (kk >> 4) * VV + w0 + (kk & 15);
        const unsigned short* up = U + (size_t)krow * NCOL + b * 384;
        *(ushort2*)&us[kk][tid * 2] = *(const ushort2*)&up[tid * 2];
    }
    __syncthreads();

    const int w = tid / 12, l = tid - w * 12;
    float acc[32];
#pragma unroll
    for (int o = 0; o < 32; o++) acc[o] = bias[o];

    // identity block in full fp32
    for (int c = 0; c < 32; c++) {
        float h = xs[c][tid];
#pragma unroll
        for (int o = 0; o < 32; o++) acc[o] += W[o * 160 + c] * h;
    }
    // graph-conv blocks
    for (int c = 0; c < 32; c++) {
#pragma unroll
        for (int k = 0; k < 4; k++) {
            float h = b2f(us[k * 16 + w][c * 12 + l]);
#pragma unroll
            for (int o = 0; o < 32; o++) acc[o] += W[o * 160 + (k + 1) * 32 + c] * h;
        }
    }

    float* yp = y + ((size_t)(b * 32) * VV + w0) * LL;
#pragma unroll
    for (int o = 0; o < 32; o++)
        yp[(size_t)o * (VV * LL) + tid] = acc[o];
}

// ---------------------------------------------------------------------------
extern "C" void kernel_launch(void* const* d_in, const int* in_sizes, int n_in,
                              void* d_out, int out_size, void* d_ws, size_t ws_size,
                              hipStream_t stream) {
    const float* x        = (const float*)d_in[0];
    const float* supports = (const float*)d_in[1];
    const float* W        = (const float*)d_in[2];
    const float* bias     = (const float*)d_in[3];
    float* y = (float*)d_out;

    char* ws = (char*)d_ws;
    unsigned short* Xb  = (unsigned short*)(ws);                 // 50,331,648 B
    unsigned short* Gt  = (unsigned short*)(ws + 50331648);      // 33,554,432 B
    unsigned short* Abf = (unsigned short*)(ws + 83886080);      // 16,777,216 B
    unsigned short* U   = (unsigned short*)(ws + 100663296);     // 201,326,592 B

    const size_t VB = (size_t)VV * VV;   // 4,194,304 elements per V x V block

    // 1. supports -> bf16 (natural layout), 2 matrices
    k_convert_bf16<<<dim3((2 * VB) / 1024), 256, 0, stream>>>(supports, Abf);

    // 2. Gt blocks 0 (A0^T) and 2 (A1^T)
    k_transpose_A<<<dim3(64, 64, 2), 256, 0, stream>>>(supports, Gt);

    // 3. (A_s^2)^T = Gt_block_s * (A_s natural)^T-form  -> Gt blocks 1 and 3
    k_gemm_bt<<<dim3(16, 16), 256, 0, stream>>>(Gt,          Abf,      Gt + VB,     VV, VV);
    k_gemm_bt<<<dim3(16, 16), 256, 0, stream>>>(Gt + 2 * VB, Abf + VB, Gt + 3 * VB, VV, VV);

    // 4. x -> Xb (transposed bf16)
    k_transpose_x<<<dim3(16, 1024), 256, 0, stream>>>(x, Xb);

    // 5. mega GEMM: U[8192 x 12288] = Gt[8192 x 2048] * Xb^T
    k_gemm_bt<<<dim3(NCOL / 128, MMEGA / 128), 256, 0, stream>>>(Gt, Xb, U, VV, NCOL);

    // 6. epilogue channel mix -> y
    k_epilogue<<<dim3(VV / 16, BB), 192, 0, stream>>>(x, U, W, bias, y);
}

// Round 2
// 914.898 us; speedup vs baseline: 1.2092x; 1.2092x over previous
//
#include <hip/hip_runtime.h>

// Problem constants
#define BB 32
#define CC 32
#define VV 2048
#define LL 12
#define NCOL 12288      // B*C*L columns of the mega GEMM
#define MMEGA 8192      // 4*V rows (k-blocks: A0, A0^2, A1, A1^2)

typedef __attribute__((ext_vector_type(8))) short bf16x8;
typedef __attribute__((ext_vector_type(4))) float f32x4;

__device__ __forceinline__ unsigned short f2b(float f) {
    union { float f; unsigned u; } v; v.f = f;
    unsigned u = v.u;
    unsigned r = (u + 0x7fffu + ((u >> 16) & 1u)) >> 16;
    return (unsigned short)r;
}
__device__ __forceinline__ float b2f(unsigned short h) {
    union { unsigned u; float f; } v; v.u = ((unsigned)h) << 16;
    return v.f;
}

__device__ __forceinline__ void stg(const unsigned short* g, unsigned short* l) {
    __builtin_amdgcn_global_load_lds((const __attribute__((address_space(1))) void*)g,
                                     (__attribute__((address_space(3))) void*)l, 16, 0, 0);
}

// ---------------------------------------------------------------------------
// Kernel 1: fp32 -> bf16 elementwise convert (supports natural layout)
__global__ void k_convert_bf16(const float* __restrict__ src,
                               unsigned short* __restrict__ dst) {
    size_t i = (size_t)(blockIdx.x * blockDim.x + threadIdx.x) * 4;
    float4 v = *(const float4*)(src + i);
    ushort4 o; o.x = f2b(v.x); o.y = f2b(v.y); o.z = f2b(v.z); o.w = f2b(v.w);
    *(ushort4*)(dst + i) = o;
}

// ---------------------------------------------------------------------------
// Kernel 2: transpose-convert A_s (fp32 [V][V]) into Gt block rows:
//   Gt[(2s)*V + w][v] = A_s[v][w]   (bf16)
__global__ void k_transpose_A(const float* __restrict__ A,
                              unsigned short* __restrict__ Gt) {
    __shared__ float t[32][33];
    const int s = blockIdx.z;
    const float* As = A + (size_t)s * VV * VV;
    const int w0 = blockIdx.x * 32, v0 = blockIdx.y * 32;
    const int tid = threadIdx.x;
    const int cc = tid & 31;
#pragma unroll
    for (int i = 0; i < 4; i++) {
        int rr = (tid >> 5) + i * 8;
        t[rr][cc] = As[(size_t)(v0 + rr) * VV + w0 + cc];
    }
    __syncthreads();
    unsigned short* G = Gt + (size_t)(2 * s) * VV * VV;
#pragma unroll
    for (int i = 0; i < 4; i++) {
        int rr = (tid >> 5) + i * 8;
        G[(size_t)(w0 + rr) * VV + v0 + cc] = f2b(t[cc][rr]);
    }
}

// ---------------------------------------------------------------------------
// Kernel 3: transpose x [B][C][V][L] fp32 -> Xb [(b*32+c)*12 + l][v] bf16
__global__ void k_transpose_x(const float* __restrict__ x,
                              unsigned short* __restrict__ Xb) {
    __shared__ float t[128 * 13];
    const int bc = blockIdx.y;
    const int v0 = blockIdx.x * 128;
    const float* xs = x + (size_t)bc * VV * LL + (size_t)v0 * LL;
    const int tid = threadIdx.x;  // 256
#pragma unroll
    for (int i = 0; i < 6; i++) {
        int e = tid + i * 256;            // 0..1535 = col*12+row
        int col = e / 12, row = e - col * 12;
        t[col * 13 + row] = xs[e];
    }
    __syncthreads();
    unsigned short* X = Xb + (size_t)bc * LL * VV + v0;
#pragma unroll
    for (int i = 0; i < 6; i++) {
        int e = tid + i * 256;
        int row = e >> 7, col = e & 127;  // row<12, col<128
        X[(size_t)row * VV + col] = f2b(t[col * 13 + row]);
    }
}

// ---------------------------------------------------------------------------
// Kernel 4: 256x256-tile 8-phase bf16 MFMA GEMM (T2+T3+T4+T5).
//   C[m,n] = sum_k Aop[m,k]*Bop[n,k], both operands K-contiguous (ld = K).
// 8 waves (2 Mx4 N), BK=64, double-buffered 128 KiB LDS, XOR slot swizzle
// (linear global_load_lds dest + pre-swizzled global source + swizzled read).
// Per K-tile: 4 phases {ds_reads; stage half-tile; bar; lgkm0; setprio+16 MFMA; bar},
// counted vmcnt(6) once per K-tile (3 half-tiles in flight).
__global__ __launch_bounds__(512, 2) void k_gemm8(
    const unsigned short* __restrict__ Ag, const unsigned short* __restrict__ Bg,
    unsigned short* __restrict__ Cg, int K, int ldc,
    size_t aStr, size_t bStr, size_t cStr)
{
    __shared__ unsigned short SH[65536];   // 128 KiB: [buf][A 16K | B 16K] elems
    const int tid  = threadIdx.x;
    const int lane = tid & 63;
    const int wid  = tid >> 6;
    const int wr   = wid >> 2;          // 0..1  (M strip of 128 rows)
    const int wc   = wid & 3;           // 0..3  (N strip of 64 rows)
    const int fr   = lane & 15;
    const int g    = lane >> 4;         // 0..3
    const int NT   = K >> 6;

    const int m0 = blockIdx.y * 256;
    const int n0 = blockIdx.x * 256;
    const unsigned short* gA = Ag + blockIdx.z * aStr + (size_t)m0 * K;
    const unsigned short* gB = Bg + blockIdx.z * bStr + (size_t)n0 * K;
    unsigned short* gC = Cg + blockIdx.z * cStr;

    // --- staging lane constants (pre-swizzled global source) ---
    const int lrow  = lane >> 3;            // row within 8-row unit
    const int lslot = (lane & 7) ^ lrow;    // XOR-swizzled 16B k-slot
    const size_t laneGOff = (size_t)lrow * K + lslot * 8;

    // unit base rows (2 units of 8 rows per wave per half-tile)
    const int qa  = wid * 16;
    const int rA0 = (qa & 63) + ((qa & 64) << 1);              // A-alpha (M0 rows)
    const int rA1 = ((qa + 8) & 63) + (((qa + 8) & 64) << 1);
    const int rB0 = (qa & 31) + ((qa & ~31) << 1);             // B-alpha (N0 rows)
    const int rB1 = ((qa + 8) & 31) + (((qa + 8) & ~31) << 1);

    // --- read-side lane constants (byte offsets, swizzled slots) ---
    const int frlow = fr & 7;
    const int sw0 = ((0 + g) ^ frlow) << 4;   // k-step 0
    const int sw1 = ((4 + g) ^ frlow) << 4;   // k-step 1
    const int aOffB = (wr * 128 + fr) * 128;  // bytes within A tile
    const int bOffB = (wc * 64  + fr) * 128;  // bytes within B tile

    f32x4 acc[8][4];
#pragma unroll
    for (int i = 0; i < 8; ++i)
#pragma unroll
        for (int j = 0; j < 4; ++j) { f32x4 z = {0.f, 0.f, 0.f, 0.f}; acc[i][j] = z; }

#define STG_A(Lb, rb, kt) stg(gA + (size_t)(rb) * K + ((size_t)(kt) << 6) + laneGOff, (Lb) + (rb) * 64)
#define STG_B(Lb, rb, kt) stg(gB + (size_t)(rb) * K + ((size_t)(kt) << 6) + laneGOff, (Lb) + (rb) * 64)
#define ST_Aa(Lb, kt) do { if ((kt) < NT) { STG_A(Lb, rA0, kt);      STG_A(Lb, rA1, kt);      } } while (0)
#define ST_Ab(Lb, kt) do { if ((kt) < NT) { STG_A(Lb, rA0 + 64, kt); STG_A(Lb, rA1 + 64, kt); } } while (0)
#define ST_Ba(Lb, kt) do { if ((kt) < NT) { STG_B(Lb, rB0, kt);      STG_B(Lb, rB1, kt);      } } while (0)
#define ST_Bb(Lb, kt) do { if ((kt) < NT) { STG_B(Lb, rB0 + 32, kt); STG_B(Lb, rB1 + 32, kt); } } while (0)
#define VM6() asm volatile("s_waitcnt vmcnt(6)" ::: "memory")
#define VM0() asm volatile("s_waitcnt vmcnt(0)" ::: "memory")
#define LGKM0() asm volatile("s_waitcnt lgkmcnt(0)" ::: "memory")
#define SBAR() __builtin_amdgcn_s_barrier()

    unsigned short* A0L = SH;
    unsigned short* B0L = SH + 16384;
    unsigned short* A1L = SH + 32768;
    unsigned short* B1L = SH + 49152;

    // Prologue: steady-state issue order; drain K-tile 0 (8 loads), keep 6 in flight.
    ST_Aa(A0L, 0); ST_Ab(A0L, 0); ST_Ba(B0L, 0); ST_Bb(B0L, 0);
    ST_Aa(A1L, 1); ST_Ab(A1L, 1); ST_Ba(B1L, 1);
    if (NT > 1) { VM6(); } else { VM0(); }
    SBAR();

    bf16x8 aM0[4][2], aM1[4][2], bN[2][2];

    for (int t = 0; t < NT; ++t) {
        const char* Ab = (const char*)(SH + ((t & 1) << 15));
        const char* Bb = Ab + 32768;                       // bytes: 16384 elems
        unsigned short* An = SH + (((t + 1) & 1) << 15);   // next buf (t+1 parity)
        unsigned short* Bn = An + 16384;
        unsigned short* Ac = SH + ((t & 1) << 15);         // current buf (t+2 parity)
        unsigned short* Bc = Ac + 16384;

        // ---- phase 1: quadrant (M0,N0); stage B-beta(t+1) ----
#pragma unroll
        for (int i = 0; i < 4; ++i) {
            aM0[i][0] = *(const bf16x8*)(Ab + aOffB + i * 2048 + sw0);
            aM0[i][1] = *(const bf16x8*)(Ab + aOffB + i * 2048 + sw1);
        }
#pragma unroll
        for (int j = 0; j < 2; ++j) {
            bN[j][0] = *(const bf16x8*)(Bb + bOffB + j * 2048 + sw0);
            bN[j][1] = *(const bf16x8*)(Bb + bOffB + j * 2048 + sw1);
        }
        ST_Bb(Bn, t + 1);
        SBAR(); LGKM0();
        __builtin_amdgcn_s_setprio(1);
#pragma unroll
        for (int i = 0; i < 4; ++i)
#pragma unroll
            for (int j = 0; j < 2; ++j) {
                acc[i][j] = __builtin_amdgcn_mfma_f32_16x16x32_bf16(aM0[i][0], bN[j][0], acc[i][j], 0, 0, 0);
                acc[i][j] = __builtin_amdgcn_mfma_f32_16x16x32_bf16(aM0[i][1], bN[j][1], acc[i][j], 0, 0, 0);
            }
        __builtin_amdgcn_s_setprio(0);
        SBAR();

        // ---- phase 2: quadrant (M1,N0); stage A-alpha(t+2) ----
#pragma unroll
        for (int i = 0; i < 4; ++i) {
            aM1[i][0] = *(const bf16x8*)(Ab + aOffB + 8192 + i * 2048 + sw0);
            aM1[i][1] = *(const bf16x8*)(Ab + aOffB + 8192 + i * 2048 + sw1);
        }
        ST_Aa(Ac, t + 2);
        SBAR(); LGKM0();
        __builtin_amdgcn_s_setprio(1);
#pragma unroll
        for (int i = 0; i < 4; ++i)
#pragma unroll
            for (int j = 0; j < 2; ++j) {
                acc[4 + i][j] = __builtin_amdgcn_mfma_f32_16x16x32_bf16(aM1[i][0], bN[j][0], acc[4 + i][j], 0, 0, 0);
                acc[4 + i][j] = __builtin_amdgcn_mfma_f32_16x16x32_bf16(aM1[i][1], bN[j][1], acc[4 + i][j], 0, 0, 0);
            }
        __builtin_amdgcn_s_setprio(0);
        SBAR();

        // ---- phase 3: quadrant (M0,N1); stage A-beta(t+2) ----
#pragma unroll
        for (int j = 0; j < 2; ++j) {
            bN[j][0] = *(const bf16x8*)(Bb + bOffB + 4096 + j * 2048 + sw0);
            bN[j][1] = *(const bf16x8*)(Bb + bOffB + 4096 + j * 2048 + sw1);
        }
        ST_Ab(Ac, t + 2);
        SBAR(); LGKM0();
        __builtin_amdgcn_s_setprio(1);
#pragma unroll
        for (int i = 0; i < 4; ++i)
#pragma unroll
            for (int j = 0; j < 2; ++j) {
                acc[i][2 + j] = __builtin_amdgcn_mfma_f32_16x16x32_bf16(aM0[i][0], bN[j][0], acc[i][2 + j], 0, 0, 0);
                acc[i][2 + j] = __builtin_amdgcn_mfma_f32_16x16x32_bf16(aM0[i][1], bN[j][1], acc[i][2 + j], 0, 0, 0);
            }
        __builtin_amdgcn_s_setprio(0);
        SBAR();

        // ---- phase 4: quadrant (M1,N1); stage B-alpha(t+2); counted vmcnt ----
        ST_Ba(Bc, t + 2);
        if (t + 2 < NT) { VM6(); } else { VM0(); }
        SBAR();
        __builtin_amdgcn_s_setprio(1);
#pragma unroll
        for (int i = 0; i < 4; ++i)
#pragma unroll
            for (int j = 0; j < 2; ++j) {
                acc[4 + i][2 + j] = __builtin_amdgcn_mfma_f32_16x16x32_bf16(aM1[i][0], bN[j][0], acc[4 + i][2 + j], 0, 0, 0);
                acc[4 + i][2 + j] = __builtin_amdgcn_mfma_f32_16x16x32_bf16(aM1[i][1], bN[j][1], acc[4 + i][2 + j], 0, 0, 0);
            }
        __builtin_amdgcn_s_setprio(0);
        SBAR();
    }

    // C write (verified 16x16x32 C/D layout: col = lane&15, row = (lane>>4)*4 + r)
    const int er = g * 4;
#pragma unroll
    for (int i = 0; i < 8; ++i)
#pragma unroll
        for (int j = 0; j < 4; ++j) {
            int row = m0 + wr * 128 + i * 16 + er;
            int col = n0 + wc * 64 + j * 16 + fr;
#pragma unroll
            for (int r = 0; r < 4; ++r)
                gC[(size_t)(row + r) * ldc + col] = f2b(acc[i][j][r]);
        }
#undef STG_A
#undef STG_B
#undef ST_Aa
#undef ST_Ab
#undef ST_Ba
#undef ST_Bb
#undef VM6
#undef VM0
#undef LGKM0
#undef SBAR
}

// ---------------------------------------------------------------------------
// Kernel 5: epilogue channel mix (fp32):
//   y[b,o,w,l] = bias[o] + sum_c W[o][c]*x[b,c,w,l]
//              + sum_{k,c} W[o][(k+1)*32+c] * U[k*V + w][(b*32+c)*12 + l]
__global__ __launch_bounds__(192) void k_epilogue(const float* __restrict__ x,
                                                  const unsigned short* __restrict__ U,
                                                  const float* __restrict__ W,
                                                  const float* __restrict__ bias,
                                                  float* __restrict__ y) {
    __shared__ float xs[32][192];            // 24 KB
    __shared__ unsigned short us[64][392];   // padded rows ~50 KB
    const int b = blockIdx.y;
    const int w0 = blockIdx.x * 16;
    const int tid = threadIdx.x;  // 0..191

    const float* xp = x + ((size_t)(b * 32) * VV + w0) * LL;
#pragma unroll 4
    for (int c = 0; c < 32; c++)
        xs[c][tid] = xp[(size_t)c * (VV * LL) + tid];

    for (int kk = 0; kk < 64; kk++) {
        int krow = (kk >> 4) * VV + w0 + (kk & 15);
        const unsigned short* up = U + (size_t)krow * NCOL + b * 384;
        *(ushort2*)&us[kk][tid * 2] = *(const ushort2*)&up[tid * 2];
    }
    __syncthreads();

    const int w = tid / 12, l = tid - w * 12;
    float acc[32];
#pragma unroll
    for (int o = 0; o < 32; o++) acc[o] = bias[o];

    for (int c = 0; c < 32; c++) {
        float h = xs[c][tid];
#pragma unroll
        for (int o = 0; o < 32; o++) acc[o] += W[o * 160 + c] * h;
    }
    for (int c = 0; c < 32; c++) {
#pragma unroll
        for (int k = 0; k < 4; k++) {
            float h = b2f(us[k * 16 + w][c * 12 + l]);
#pragma unroll
            for (int o = 0; o < 32; o++) acc[o] += W[o * 160 + (k + 1) * 32 + c] * h;
        }
    }

    float* yp = y + ((size_t)(b * 32) * VV + w0) * LL;
#pragma unroll
    for (int o = 0; o < 32; o++)
        yp[(size_t)o * (VV * LL) + tid] = acc[o];
}

// ---------------------------------------------------------------------------
extern "C" void kernel_launch(void* const* d_in, const int* in_sizes, int n_in,
                              void* d_out, int out_size, void* d_ws, size_t ws_size,
                              hipStream_t stream) {
    const float* x        = (const float*)d_in[0];
    const float* supports = (const float*)d_in[1];
    const float* W        = (const float*)d_in[2];
    const float* bias     = (const float*)d_in[3];
    float* y = (float*)d_out;

    char* ws = (char*)d_ws;
    unsigned short* Xb  = (unsigned short*)(ws);                 // 50,331,648 B
    unsigned short* Gt  = (unsigned short*)(ws + 50331648);      // 33,554,432 B
    unsigned short* Abf = (unsigned short*)(ws + 83886080);      // 16,777,216 B
    unsigned short* U   = (unsigned short*)(ws + 100663296);     // 201,326,592 B

    const size_t VB = (size_t)VV * VV;   // 4,194,304 elements per V x V block

    // 1. supports -> bf16 (natural layout), 2 matrices
    k_convert_bf16<<<dim3((2 * VB) / 1024), 256, 0, stream>>>(supports, Abf);

    // 2. Gt blocks 0 (A0^T) and 2 (A1^T)
    k_transpose_A<<<dim3(64, 64, 2), 256, 0, stream>>>(supports, Gt);

    // 3. (A_s^2)^T -> Gt blocks 1 and 3 (both supports in one dispatch, z=2)
    k_gemm8<<<dim3(8, 8, 2), 512, 0, stream>>>(Gt, Abf, Gt + VB, VV, VV,
                                               2 * VB, VB, 2 * VB);

    // 4. x -> Xb (transposed bf16)
    k_transpose_x<<<dim3(16, 1024), 256, 0, stream>>>(x, Xb);

    // 5. mega GEMM: U[8192 x 12288] = Gt[8192 x 2048] * Xb^T
    k_gemm8<<<dim3(NCOL / 256, MMEGA / 256, 1), 512, 0, stream>>>(Gt, Xb, U, VV, NCOL,
                                                                  0, 0, 0);

    // 6. epilogue channel mix -> y
    k_epilogue<<<dim3(VV / 16, BB), 192, 0, stream>>>(x, U, W, bias, y);
}

// Round 4
// 850.014 us; speedup vs baseline: 1.3015x; 1.0763x over previous
//
#include <hip/hip_runtime.h>

// Problem constants
#define BB 32
#define CC 32
#define VV 2048
#define LL 12
#define NCOL 12288      // B*C*L columns of the mega GEMM
#define MMEGA 8192      // 4*V rows (k-blocks: A0, A0^2, A1, A1^2)

typedef __attribute__((ext_vector_type(8))) short bf16x8;
typedef __attribute__((ext_vector_type(4))) float f32x4;

__device__ __forceinline__ unsigned short f2b(float f) {
    union { float f; unsigned u; } v; v.f = f;
    unsigned u = v.u;
    unsigned r = (u + 0x7fffu + ((u >> 16) & 1u)) >> 16;
    return (unsigned short)r;
}
__device__ __forceinline__ float b2f(unsigned short h) {
    union { unsigned u; float f; } v; v.u = ((unsigned)h) << 16;
    return v.f;
}

__device__ __forceinline__ void stg(const unsigned short* g, unsigned short* l) {
    __builtin_amdgcn_global_load_lds((const __attribute__((address_space(1))) void*)g,
                                     (__attribute__((address_space(3))) void*)l, 16, 0, 0);
}

// ---------------------------------------------------------------------------
// Kernel 1: merged convert + transpose of supports.
//   Abf[s][v][w] = bf16(A_s[v][w]);  Gt[(2s)*V + w][v] = bf16(A_s[v][w])
__global__ void k_prepA(const float* __restrict__ A,
                        unsigned short* __restrict__ Abf,
                        unsigned short* __restrict__ Gt) {
    __shared__ float t[32][33];
    const int s = blockIdx.z;
    const float* As = A + (size_t)s * VV * VV;
    const int w0 = blockIdx.x * 32, v0 = blockIdx.y * 32;
    const int tid = threadIdx.x;
    const int cc = tid & 31;
    unsigned short* Ao = Abf + (size_t)s * VV * VV;
#pragma unroll
    for (int i = 0; i < 4; i++) {
        int rr = (tid >> 5) + i * 8;
        float val = As[(size_t)(v0 + rr) * VV + w0 + cc];
        t[rr][cc] = val;
        Ao[(size_t)(v0 + rr) * VV + w0 + cc] = f2b(val);
    }
    __syncthreads();
    unsigned short* G = Gt + (size_t)(2 * s) * VV * VV;
#pragma unroll
    for (int i = 0; i < 4; i++) {
        int rr = (tid >> 5) + i * 8;
        G[(size_t)(w0 + rr) * VV + v0 + cc] = f2b(t[cc][rr]);
    }
}

// ---------------------------------------------------------------------------
// Kernel 2: transpose x [B][C][V][L] fp32 -> Xb [(b*32+c)*12 + l][v] bf16
__global__ void k_transpose_x(const float* __restrict__ x,
                              unsigned short* __restrict__ Xb) {
    __shared__ float t[128 * 13];
    const int bc = blockIdx.y;
    const int v0 = blockIdx.x * 128;
    const float* xs = x + (size_t)bc * VV * LL + (size_t)v0 * LL;
    const int tid = threadIdx.x;  // 256
#pragma unroll
    for (int i = 0; i < 6; i++) {
        int e = tid + i * 256;            // 0..1535 = col*12+row
        int col = e / 12, row = e - col * 12;
        t[col * 13 + row] = xs[e];
    }
    __syncthreads();
    unsigned short* X = Xb + (size_t)bc * LL * VV + v0;
#pragma unroll
    for (int i = 0; i < 2; i++) {
        int flat = tid + i * 256;         // 384 ushort4 chunks: 12 rows x 32
        if (flat < 384) {
            int row = flat >> 5;
            int col = (flat & 31) * 4;
            ushort4 o;
            o.x = f2b(t[(col + 0) * 13 + row]);
            o.y = f2b(t[(col + 1) * 13 + row]);
            o.z = f2b(t[(col + 2) * 13 + row]);
            o.w = f2b(t[(col + 3) * 13 + row]);
            *(ushort4*)&X[(size_t)row * VV + col] = o;
        }
    }
}

// ---------------------------------------------------------------------------
// Kernel 3: 256x256-tile 8-phase bf16 MFMA GEMM (T2+T3+T4+T5) with
// one-phase-ahead register fragment pipeline (counted lgkmcnt).
//   C[m,n] = sum_k Aop[m,k]*Bop[n,k], both operands K-contiguous (ld = K).
__global__ __launch_bounds__(512, 2) void k_gemm8(
    const unsigned short* __restrict__ Ag, const unsigned short* __restrict__ Bg,
    unsigned short* __restrict__ Cg, int K, int ldc,
    size_t aStr, size_t bStr, size_t cStr)
{
    __shared__ unsigned short SH[65536];   // 128 KiB: [buf][A 16K | B 16K] elems
    const int tid  = threadIdx.x;
    const int lane = tid & 63;
    const int wid  = tid >> 6;
    const int wr   = wid >> 2;          // 0..1  (M strip of 128 rows)
    const int wc   = wid & 3;           // 0..3  (N strip of 64 rows)
    const int fr   = lane & 15;
    const int g    = lane >> 4;         // 0..3
    const int NT   = K >> 6;

    const int m0 = blockIdx.y * 256;
    const int n0 = blockIdx.x * 256;
    const unsigned short* gA = Ag + blockIdx.z * aStr + (size_t)m0 * K;
    const unsigned short* gB = Bg + blockIdx.z * bStr + (size_t)n0 * K;
    unsigned short* gC = Cg + blockIdx.z * cStr;

    // --- staging lane constants (pre-swizzled global source) ---
    const int lrow  = lane >> 3;            // row within 8-row unit
    const int lslot = (lane & 7) ^ lrow;    // XOR-swizzled 16B k-slot
    const size_t laneGOff = (size_t)lrow * K + lslot * 8;

    // unit base rows (2 units of 8 rows per wave per half-tile)
    const int qa  = wid * 16;
    const int rA0 = (qa & 63) + ((qa & 64) << 1);              // A-alpha rows
    const int rA1 = ((qa + 8) & 63) + (((qa + 8) & 64) << 1);
    const int rB0 = (qa & 31) + ((qa & ~31) << 1);             // B-alpha rows
    const int rB1 = ((qa + 8) & 31) + (((qa + 8) & ~31) << 1);

    // --- read-side lane constants (byte offsets, swizzled slots) ---
    const int frlow = fr & 7;
    const int sw0 = ((0 + g) ^ frlow) << 4;   // k-step 0
    const int sw1 = ((4 + g) ^ frlow) << 4;   // k-step 1
    const int aOffB = (wr * 128 + fr) * 128;  // bytes within A tile
    const int bOffB = (wc * 64  + fr) * 128;  // bytes within B tile

    f32x4 acc[8][4];
#pragma unroll
    for (int i = 0; i < 8; ++i)
#pragma unroll
        for (int j = 0; j < 4; ++j) { f32x4 z = {0.f, 0.f, 0.f, 0.f}; acc[i][j] = z; }

#define STG_A(Lb, rb, kt) stg(gA + (size_t)(rb) * K + ((size_t)(kt) << 6) + laneGOff, (Lb) + (rb) * 64)
#define STG_B(Lb, rb, kt) stg(gB + (size_t)(rb) * K + ((size_t)(kt) << 6) + laneGOff, (Lb) + (rb) * 64)
#define ST_Aa(Lb, kt) do { if ((kt) < NT) { STG_A(Lb, rA0, kt);      STG_A(Lb, rA1, kt);      } } while (0)
#define ST_Ab(Lb, kt) do { if ((kt) < NT) { STG_A(Lb, rA0 + 64, kt); STG_A(Lb, rA1 + 64, kt); } } while (0)
#define ST_Ba(Lb, kt) do { if ((kt) < NT) { STG_B(Lb, rB0, kt);      STG_B(Lb, rB1, kt);      } } while (0)
#define ST_Bb(Lb, kt) do { if ((kt) < NT) { STG_B(Lb, rB0 + 32, kt); STG_B(Lb, rB1 + 32, kt); } } while (0)
#define VM6() asm volatile("s_waitcnt vmcnt(6)" ::: "memory")
#define VM0() asm volatile("s_waitcnt vmcnt(0)" ::: "memory")
#define LGKM(n) asm volatile("s_waitcnt lgkmcnt(" #n ")" ::: "memory")
#define SCHB() __builtin_amdgcn_sched_barrier(0)
#define SBAR() __builtin_amdgcn_s_barrier()

    unsigned short* A0L = SH;
    unsigned short* B0L = SH + 16384;
    unsigned short* A1L = SH + 32768;
    unsigned short* B1L = SH + 49152;

    // Prologue: stage 7 half-tile units; vmcnt(6) -> all of tile 0 landed.
    ST_Aa(A0L, 0); ST_Ab(A0L, 0); ST_Ba(B0L, 0); ST_Bb(B0L, 0);
    ST_Aa(A1L, 1); ST_Ab(A1L, 1); ST_Ba(B1L, 1);
    if (NT > 1) { VM6(); } else { VM0(); }
    SBAR();

    // Fragment register sets (one-phase-ahead pipeline):
    //   aA = A rows [wr*128, +63]   (read in P4 of prev tile, used P1/P3)
    //   aB = A rows [wr*128+64,+63] (read P1, used P2/P4)
    //   b0 = B rows [wc*64, +31]    (read P4 prev, used P1/P2)
    //   b1 = B rows [wc*64+32,+31]  (read P2, used P3/P4)
    bf16x8 aA[4][2], aB[4][2], b0[2][2], b1[2][2];
    {
        const char* Ab = (const char*)SH;
        const char* Bb = Ab + 32768;
#pragma unroll
        for (int i = 0; i < 4; ++i) {
            aA[i][0] = *(const bf16x8*)(Ab + aOffB + i * 2048 + sw0);
            aA[i][1] = *(const bf16x8*)(Ab + aOffB + i * 2048 + sw1);
        }
#pragma unroll
        for (int j = 0; j < 2; ++j) {
            b0[j][0] = *(const bf16x8*)(Bb + bOffB + j * 2048 + sw0);
            b0[j][1] = *(const bf16x8*)(Bb + bOffB + j * 2048 + sw1);
        }
    }

    for (int t = 0; t < NT; ++t) {
        const char* Ab  = (const char*)(SH + ((t & 1) << 15));
        const char* Bb  = Ab + 32768;
        const char* AbN = (const char*)(SH + (((t + 1) & 1) << 15));
        const char* BbN = AbN + 32768;
        unsigned short* An = SH + (((t + 1) & 1) << 15);
        unsigned short* Bn = An + 16384;
        unsigned short* Ac = SH + ((t & 1) << 15);
        unsigned short* Bc = Ac + 16384;
        (void)An;

        // ---- P1: read aB(t); stage B-beta(t+1); MFMA Q(M0,N0) w/ aA,b0 ----
#pragma unroll
        for (int i = 0; i < 4; ++i) {
            aB[i][0] = *(const bf16x8*)(Ab + aOffB + 8192 + i * 2048 + sw0);
            aB[i][1] = *(const bf16x8*)(Ab + aOffB + 8192 + i * 2048 + sw1);
        }
        ST_Bb(Bn, t + 1);
        SBAR(); LGKM(8); SCHB();
        __builtin_amdgcn_s_setprio(1);
#pragma unroll
        for (int i = 0; i < 4; ++i)
#pragma unroll
            for (int j = 0; j < 2; ++j) {
                acc[i][j] = __builtin_amdgcn_mfma_f32_16x16x32_bf16(aA[i][0], b0[j][0], acc[i][j], 0, 0, 0);
                acc[i][j] = __builtin_amdgcn_mfma_f32_16x16x32_bf16(aA[i][1], b0[j][1], acc[i][j], 0, 0, 0);
            }
        __builtin_amdgcn_s_setprio(0);
        SBAR();

        // ---- P2: read b1(t); stage A-alpha(t+2); MFMA Q(M1,N0) w/ aB,b0 ----
#pragma unroll
        for (int j = 0; j < 2; ++j) {
            b1[j][0] = *(const bf16x8*)(Bb + bOffB + 4096 + j * 2048 + sw0);
            b1[j][1] = *(const bf16x8*)(Bb + bOffB + 4096 + j * 2048 + sw1);
        }
        ST_Aa(Ac, t + 2);
        SBAR(); LGKM(4); SCHB();
        __builtin_amdgcn_s_setprio(1);
#pragma unroll
        for (int i = 0; i < 4; ++i)
#pragma unroll
            for (int j = 0; j < 2; ++j) {
                acc[4 + i][j] = __builtin_amdgcn_mfma_f32_16x16x32_bf16(aB[i][0], b0[j][0], acc[4 + i][j], 0, 0, 0);
                acc[4 + i][j] = __builtin_amdgcn_mfma_f32_16x16x32_bf16(aB[i][1], b0[j][1], acc[4 + i][j], 0, 0, 0);
            }
        __builtin_amdgcn_s_setprio(0);
        SBAR();

        // ---- P3: stage A-beta(t+2); MFMA Q(M0,N1) w/ aA,b1 ----
        ST_Ab(Ac, t + 2);
        SBAR(); LGKM(0); SCHB();
        __builtin_amdgcn_s_setprio(1);
#pragma unroll
        for (int i = 0; i < 4; ++i)
#pragma unroll
            for (int j = 0; j < 2; ++j) {
                acc[i][2 + j] = __builtin_amdgcn_mfma_f32_16x16x32_bf16(aA[i][0], b1[j][0], acc[i][2 + j], 0, 0, 0);
                acc[i][2 + j] = __builtin_amdgcn_mfma_f32_16x16x32_bf16(aA[i][1], b1[j][1], acc[i][2 + j], 0, 0, 0);
            }
        __builtin_amdgcn_s_setprio(0);
        SBAR();

        // ---- P4: stage B-alpha(t+2); counted vmcnt; read aA,b0(t+1) from
        //          next buffer (guaranteed landed post-VM6); MFMA Q(M1,N1) ----
        ST_Ba(Bc, t + 2);
        if (t + 2 < NT) { VM6(); } else { VM0(); }
        SBAR();
#pragma unroll
        for (int i = 0; i < 4; ++i) {
            aA[i][0] = *(const bf16x8*)(AbN + aOffB + i * 2048 + sw0);
            aA[i][1] = *(const bf16x8*)(AbN + aOffB + i * 2048 + sw1);
        }
#pragma unroll
        for (int j = 0; j < 2; ++j) {
            b0[j][0] = *(const bf16x8*)(BbN + bOffB + j * 2048 + sw0);
            b0[j][1] = *(const bf16x8*)(BbN + bOffB + j * 2048 + sw1);
        }
        LGKM(12); SCHB();
        __builtin_amdgcn_s_setprio(1);
#pragma unroll
        for (int i = 0; i < 4; ++i)
#pragma unroll
            for (int j = 0; j < 2; ++j) {
                acc[4 + i][2 + j] = __builtin_amdgcn_mfma_f32_16x16x32_bf16(aB[i][0], b1[j][0], acc[4 + i][2 + j], 0, 0, 0);
                acc[4 + i][2 + j] = __builtin_amdgcn_mfma_f32_16x16x32_bf16(aB[i][1], b1[j][1], acc[4 + i][2 + j], 0, 0, 0);
            }
        __builtin_amdgcn_s_setprio(0);
        SBAR();
    }

    // C write (verified 16x16x32 C/D layout: col = lane&15, row = (lane>>4)*4 + r)
    const int er = g * 4;
#pragma unroll
    for (int i = 0; i < 8; ++i)
#pragma unroll
        for (int j = 0; j < 4; ++j) {
            int row = m0 + wr * 128 + i * 16 + er;
            int col = n0 + wc * 64 + j * 16 + fr;
#pragma unroll
            for (int r = 0; r < 4; ++r)
                gC[(size_t)(row + r) * ldc + col] = f2b(acc[i][j][r]);
        }
#undef STG_A
#undef STG_B
#undef ST_Aa
#undef ST_Ab
#undef ST_Ba
#undef ST_Bb
#undef VM6
#undef VM0
#undef LGKM
#undef SCHB
#undef SBAR
}

// ---------------------------------------------------------------------------
// Kernel 4: epilogue channel mix (fp32):
//   y[b,o,w,l] = bias[o] + sum_c W[o][c]*x[b,c,w,l]
//              + sum_{k,c} W[o][(k+1)*32+c] * U[k*V + w][(b*32+c)*12 + l]
__global__ __launch_bounds__(192) void k_epilogue(const float* __restrict__ x,
                                                  const unsigned short* __restrict__ U,
                                                  const float* __restrict__ W,
                                                  const float* __restrict__ bias,
                                                  float* __restrict__ y) {
    __shared__ float xs[32][192];            // 24 KB
    __shared__ unsigned short us[64][392];   // padded rows (784 B, 16B-mult) ~50 KB
    const int b = blockIdx.y;
    const int w0 = blockIdx.x * 16;
    const int tid = threadIdx.x;  // 0..191

    const float* xp = x + ((size_t)(b * 32) * VV + w0) * LL;
#pragma unroll 4
    for (int c = 0; c < 32; c++)
        xs[c][tid] = xp[(size_t)c * (VV * LL) + tid];

    // U staging: 64 rows x 768 B, b128 chunks, 4 rows x 48 chunks per pass
    {
        const int r0 = tid / 48;          // 0..3
        const int c0 = tid - r0 * 48;     // 0..47
#pragma unroll
        for (int it = 0; it < 16; ++it) {
            int r = it * 4 + r0;          // 0..63
            int krow = (r >> 4) * VV + w0 + (r & 15);
            const unsigned short* up = U + (size_t)krow * NCOL + b * 384 + c0 * 8;
            *(bf16x8*)&us[r][c0 * 8] = *(const bf16x8*)up;
        }
    }
    __syncthreads();

    const int w = tid / 12, l = tid - w * 12;
    float acc[32];
#pragma unroll
    for (int o = 0; o < 32; o++) acc[o] = bias[o];

    for (int c = 0; c < 32; c++) {
        float h = xs[c][tid];
#pragma unroll
        for (int o = 0; o < 32; o++) acc[o] += W[o * 160 + c] * h;
    }
    for (int c = 0; c < 32; c++) {
#pragma unroll
        for (int k = 0; k < 4; k++) {
            float h = b2f(us[k * 16 + w][c * 12 + l]);
#pragma unroll
            for (int o = 0; o < 32; o++) acc[o] += W[o * 160 + (k + 1) * 32 + c] * h;
        }
    }

    float* yp = y + ((size_t)(b * 32) * VV + w0) * LL;
#pragma unroll
    for (int o = 0; o < 32; o++)
        yp[(size_t)o * (VV * LL) + tid] = acc[o];
}

// ---------------------------------------------------------------------------
extern "C" void kernel_launch(void* const* d_in, const int* in_sizes, int n_in,
                              void* d_out, int out_size, void* d_ws, size_t ws_size,
                              hipStream_t stream) {
    const float* x        = (const float*)d_in[0];
    const float* supports = (const float*)d_in[1];
    const float* W        = (const float*)d_in[2];
    const float* bias     = (const float*)d_in[3];
    float* y = (float*)d_out;

    char* ws = (char*)d_ws;
    unsigned short* Xb  = (unsigned short*)(ws);                 // 50,331,648 B
    unsigned short* Gt  = (unsigned short*)(ws + 50331648);      // 33,554,432 B
    unsigned short* Abf = (unsigned short*)(ws + 83886080);      // 16,777,216 B
    unsigned short* U   = (unsigned short*)(ws + 100663296);     // 201,326,592 B

    const size_t VB = (size_t)VV * VV;   // 4,194,304 elements per V x V block

    // 1. supports -> Abf (bf16 natural) + Gt blocks 0,2 (transposed), fused
    k_prepA<<<dim3(64, 64, 2), 256, 0, stream>>>(supports, Abf, Gt);

    // 2. (A_s^2)^T -> Gt blocks 1 and 3 (both supports, z=2)
    k_gemm8<<<dim3(8, 8, 2), 512, 0, stream>>>(Gt, Abf, Gt + VB, VV, VV,
                                               2 * VB, VB, 2 * VB);

    // 3. x -> Xb (transposed bf16)
    k_transpose_x<<<dim3(16, 1024), 256, 0, stream>>>(x, Xb);

    // 4. mega GEMM: U[8192 x 12288] = Gt[8192 x 2048] * Xb^T
    k_gemm8<<<dim3(NCOL / 256, MMEGA / 256, 1), 512, 0, stream>>>(Gt, Xb, U, VV, NCOL,
                                                                  0, 0, 0);

    // 5. epilogue channel mix -> y
    k_epilogue<<<dim3(VV / 16, BB), 192, 0, stream>>>(x, U, W, bias, y);
}

// Round 5
// 833.686 us; speedup vs baseline: 1.3270x; 1.0196x over previous
//
#include <hip/hip_runtime.h>

// Problem constants
#define BB 32
#define CC 32
#define VV 2048
#define LL 12
#define NCOL 12288      // B*C*L columns of the mega GEMM
#define MMEGA 8192      // 4*V rows (k-blocks: A0, A0^2, A1, A1^2)
#define VB ((size_t)VV * VV)

typedef __attribute__((ext_vector_type(8))) short bf16x8;
typedef __attribute__((ext_vector_type(4))) float f32x4;

__device__ __forceinline__ unsigned short f2b(float f) {
    union { float f; unsigned u; } v; v.f = f;
    unsigned u = v.u;
    unsigned r = (u + 0x7fffu + ((u >> 16) & 1u)) >> 16;
    return (unsigned short)r;
}
__device__ __forceinline__ float b2f(unsigned short h) {
    union { unsigned u; float f; } v; v.u = ((unsigned)h) << 16;
    return v.f;
}

__device__ __forceinline__ void stg(const unsigned short* g, unsigned short* l) {
    __builtin_amdgcn_global_load_lds((const __attribute__((address_space(1))) void*)g,
                                     (__attribute__((address_space(3))) void*)l, 16, 0, 0);
}

// ---------------------------------------------------------------------------
// Kernel 1: merged convert + transpose of supports.
//   Abf[s][v][w] = bf16(A_s[v][w]);  Gt[(2s)*V + w][v] = bf16(A_s[v][w])
__global__ void k_prepA(const float* __restrict__ A,
                        unsigned short* __restrict__ Abf,
                        unsigned short* __restrict__ Gt) {
    __shared__ float t[32][33];
    const int s = blockIdx.z;
    const float* As = A + (size_t)s * VB;
    const int w0 = blockIdx.x * 32, v0 = blockIdx.y * 32;
    const int tid = threadIdx.x;
    const int cc = tid & 31;
    unsigned short* Ao = Abf + (size_t)s * VB;
#pragma unroll
    for (int i = 0; i < 4; i++) {
        int rr = (tid >> 5) + i * 8;
        float val = As[(size_t)(v0 + rr) * VV + w0 + cc];
        t[rr][cc] = val;
        Ao[(size_t)(v0 + rr) * VV + w0 + cc] = f2b(val);
    }
    __syncthreads();
    unsigned short* G = Gt + (size_t)(2 * s) * VB;
#pragma unroll
    for (int i = 0; i < 4; i++) {
        int rr = (tid >> 5) + i * 8;
        G[(size_t)(w0 + rr) * VV + v0 + cc] = f2b(t[cc][rr]);
    }
}

// ---------------------------------------------------------------------------
// Kernel 2: transpose x [B][C][V][L] fp32 -> Xb [(b*32+c)*12 + l][v] bf16
__global__ void k_transpose_x(const float* __restrict__ x,
                              unsigned short* __restrict__ Xb) {
    __shared__ float t[128 * 13];
    const int bc = blockIdx.y;
    const int v0 = blockIdx.x * 128;
    const float* xs = x + (size_t)bc * VV * LL + (size_t)v0 * LL;
    const int tid = threadIdx.x;  // 256
#pragma unroll
    for (int i = 0; i < 6; i++) {
        int e = tid + i * 256;            // 0..1535 = col*12+row
        int col = e / 12, row = e - col * 12;
        t[col * 13 + row] = xs[e];
    }
    __syncthreads();
    unsigned short* X = Xb + (size_t)bc * LL * VV + v0;
#pragma unroll
    for (int i = 0; i < 2; i++) {
        int flat = tid + i * 256;         // 384 ushort4 chunks: 12 rows x 32
        if (flat < 384) {
            int row = flat >> 5;
            int col = (flat & 31) * 4;
            ushort4 o;
            o.x = f2b(t[(col + 0) * 13 + row]);
            o.y = f2b(t[(col + 1) * 13 + row]);
            o.z = f2b(t[(col + 2) * 13 + row]);
            o.w = f2b(t[(col + 3) * 13 + row]);
            *(ushort4*)&X[(size_t)row * VV + col] = o;
        }
    }
}

// ---------------------------------------------------------------------------
// Core: 256x256-tile 8-phase bf16 MFMA GEMM (T2+T3+T4+T5), one-phase-ahead
// register fragment pipeline, counted vmcnt(6)/lgkmcnt.
//   C[m,n] = sum_{k in [koff, koff+Kloc)} Aop[m0+m, k] * Bop[n0+n, k]
// Both operands row-stride ld, K-contiguous. F32OUT: write fp32 (split-K
// partials) instead of bf16.
template<bool F32OUT>
__device__ __forceinline__ void gemm_core(const unsigned short* __restrict__ Ag,
                                          const unsigned short* __restrict__ Bg,
                                          void* __restrict__ Cg,
                                          int ld, int Kloc, int koff,
                                          int m0, int n0, int ldc)
{
    __shared__ unsigned short SH[65536];   // 128 KiB: [buf][A 16K | B 16K] elems
    const int tid  = threadIdx.x;
    const int lane = tid & 63;
    const int wid  = tid >> 6;
    const int wr   = wid >> 2;          // 0..1  (M strip of 128 rows)
    const int wc   = wid & 3;           // 0..3  (N strip of 64 rows)
    const int fr   = lane & 15;
    const int g    = lane >> 4;         // 0..3
    const int NT   = Kloc >> 6;

    const unsigned short* gA = Ag + (size_t)m0 * ld + koff;
    const unsigned short* gB = Bg + (size_t)n0 * ld + koff;

    // --- staging lane constants (pre-swizzled global source) ---
    const int lrow  = lane >> 3;            // row within 8-row unit
    const int lslot = (lane & 7) ^ lrow;    // XOR-swizzled 16B k-slot
    const size_t laneGOff = (size_t)lrow * ld + lslot * 8;

    // unit base rows (2 units of 8 rows per wave per half-tile)
    const int qa  = wid * 16;
    const int rA0 = (qa & 63) + ((qa & 64) << 1);              // A-alpha rows
    const int rA1 = ((qa + 8) & 63) + (((qa + 8) & 64) << 1);
    const int rB0 = (qa & 31) + ((qa & ~31) << 1);             // B-alpha rows
    const int rB1 = ((qa + 8) & 31) + (((qa + 8) & ~31) << 1);

    // --- read-side lane constants (byte offsets, swizzled slots) ---
    const int frlow = fr & 7;
    const int sw0 = ((0 + g) ^ frlow) << 4;   // k-step 0
    const int sw1 = ((4 + g) ^ frlow) << 4;   // k-step 1
    const int aOffB = (wr * 128 + fr) * 128;  // bytes within A tile
    const int bOffB = (wc * 64  + fr) * 128;  // bytes within B tile

    f32x4 acc[8][4];
#pragma unroll
    for (int i = 0; i < 8; ++i)
#pragma unroll
        for (int j = 0; j < 4; ++j) { f32x4 z = {0.f, 0.f, 0.f, 0.f}; acc[i][j] = z; }

#define STG_A(Lb, rb, kt) stg(gA + (size_t)(rb) * ld + ((size_t)(kt) << 6) + laneGOff, (Lb) + (rb) * 64)
#define STG_B(Lb, rb, kt) stg(gB + (size_t)(rb) * ld + ((size_t)(kt) << 6) + laneGOff, (Lb) + (rb) * 64)
#define ST_Aa(Lb, kt) do { if ((kt) < NT) { STG_A(Lb, rA0, kt);      STG_A(Lb, rA1, kt);      } } while (0)
#define ST_Ab(Lb, kt) do { if ((kt) < NT) { STG_A(Lb, rA0 + 64, kt); STG_A(Lb, rA1 + 64, kt); } } while (0)
#define ST_Ba(Lb, kt) do { if ((kt) < NT) { STG_B(Lb, rB0, kt);      STG_B(Lb, rB1, kt);      } } while (0)
#define ST_Bb(Lb, kt) do { if ((kt) < NT) { STG_B(Lb, rB0 + 32, kt); STG_B(Lb, rB1 + 32, kt); } } while (0)
#define VM6() asm volatile("s_waitcnt vmcnt(6)" ::: "memory")
#define VM0() asm volatile("s_waitcnt vmcnt(0)" ::: "memory")
#define LGKM(n) asm volatile("s_waitcnt lgkmcnt(" #n ")" ::: "memory")
#define SCHB() __builtin_amdgcn_sched_barrier(0)
#define SBAR() __builtin_amdgcn_s_barrier()

    unsigned short* A0L = SH;
    unsigned short* B0L = SH + 16384;
    unsigned short* A1L = SH + 32768;
    unsigned short* B1L = SH + 49152;

    // Prologue: stage 7 half-tile units; vmcnt(6) -> all of tile 0 landed.
    ST_Aa(A0L, 0); ST_Ab(A0L, 0); ST_Ba(B0L, 0); ST_Bb(B0L, 0);
    ST_Aa(A1L, 1); ST_Ab(A1L, 1); ST_Ba(B1L, 1);
    if (NT > 1) { VM6(); } else { VM0(); }
    SBAR();

    // Fragment register sets (one-phase-ahead pipeline):
    //   aA = A rows [wr*128, +63]   (read in P4 of prev tile, used P1/P3)
    //   aB = A rows [wr*128+64,+63] (read P1, used P2/P4)
    //   b0 = B rows [wc*64, +31]    (read P4 prev, used P1/P2)
    //   b1 = B rows [wc*64+32,+31]  (read P2, used P3/P4)
    bf16x8 aA[4][2], aB[4][2], b0[2][2], b1[2][2];
    {
        const char* Ab = (const char*)SH;
        const char* Bb = Ab + 32768;
#pragma unroll
        for (int i = 0; i < 4; ++i) {
            aA[i][0] = *(const bf16x8*)(Ab + aOffB + i * 2048 + sw0);
            aA[i][1] = *(const bf16x8*)(Ab + aOffB + i * 2048 + sw1);
        }
#pragma unroll
        for (int j = 0; j < 2; ++j) {
            b0[j][0] = *(const bf16x8*)(Bb + bOffB + j * 2048 + sw0);
            b0[j][1] = *(const bf16x8*)(Bb + bOffB + j * 2048 + sw1);
        }
    }

    for (int t = 0; t < NT; ++t) {
        const char* Ab  = (const char*)(SH + ((t & 1) << 15));
        const char* Bb  = Ab + 32768;
        const char* AbN = (const char*)(SH + (((t + 1) & 1) << 15));
        const char* BbN = AbN + 32768;
        unsigned short* An = SH + (((t + 1) & 1) << 15);
        unsigned short* Bn = An + 16384;
        unsigned short* Ac = SH + ((t & 1) << 15);
        unsigned short* Bc = Ac + 16384;
        (void)An;

        // ---- P1: read aB(t); stage B-beta(t+1); MFMA Q(M0,N0) w/ aA,b0 ----
#pragma unroll
        for (int i = 0; i < 4; ++i) {
            aB[i][0] = *(const bf16x8*)(Ab + aOffB + 8192 + i * 2048 + sw0);
            aB[i][1] = *(const bf16x8*)(Ab + aOffB + 8192 + i * 2048 + sw1);
        }
        ST_Bb(Bn, t + 1);
        SBAR(); LGKM(8); SCHB();
        __builtin_amdgcn_s_setprio(1);
#pragma unroll
        for (int i = 0; i < 4; ++i)
#pragma unroll
            for (int j = 0; j < 2; ++j) {
                acc[i][j] = __builtin_amdgcn_mfma_f32_16x16x32_bf16(aA[i][0], b0[j][0], acc[i][j], 0, 0, 0);
                acc[i][j] = __builtin_amdgcn_mfma_f32_16x16x32_bf16(aA[i][1], b0[j][1], acc[i][j], 0, 0, 0);
            }
        __builtin_amdgcn_s_setprio(0);
        SBAR();

        // ---- P2: read b1(t); stage A-alpha(t+2); MFMA Q(M1,N0) w/ aB,b0 ----
#pragma unroll
        for (int j = 0; j < 2; ++j) {
            b1[j][0] = *(const bf16x8*)(Bb + bOffB + 4096 + j * 2048 + sw0);
            b1[j][1] = *(const bf16x8*)(Bb + bOffB + 4096 + j * 2048 + sw1);
        }
        ST_Aa(Ac, t + 2);
        SBAR(); LGKM(4); SCHB();
        __builtin_amdgcn_s_setprio(1);
#pragma unroll
        for (int i = 0; i < 4; ++i)
#pragma unroll
            for (int j = 0; j < 2; ++j) {
                acc[4 + i][j] = __builtin_amdgcn_mfma_f32_16x16x32_bf16(aB[i][0], b0[j][0], acc[4 + i][j], 0, 0, 0);
                acc[4 + i][j] = __builtin_amdgcn_mfma_f32_16x16x32_bf16(aB[i][1], b0[j][1], acc[4 + i][j], 0, 0, 0);
            }
        __builtin_amdgcn_s_setprio(0);
        SBAR();

        // ---- P3: stage A-beta(t+2); MFMA Q(M0,N1) w/ aA,b1 ----
        ST_Ab(Ac, t + 2);
        SBAR(); LGKM(0); SCHB();
        __builtin_amdgcn_s_setprio(1);
#pragma unroll
        for (int i = 0; i < 4; ++i)
#pragma unroll
            for (int j = 0; j < 2; ++j) {
                acc[i][2 + j] = __builtin_amdgcn_mfma_f32_16x16x32_bf16(aA[i][0], b1[j][0], acc[i][2 + j], 0, 0, 0);
                acc[i][2 + j] = __builtin_amdgcn_mfma_f32_16x16x32_bf16(aA[i][1], b1[j][1], acc[i][2 + j], 0, 0, 0);
            }
        __builtin_amdgcn_s_setprio(0);
        SBAR();

        // ---- P4: stage B-alpha(t+2); counted vmcnt; read aA,b0(t+1) from
        //          next buffer (guaranteed landed post-VM6); MFMA Q(M1,N1) ----
        ST_Ba(Bc, t + 2);
        if (t + 2 < NT) { VM6(); } else { VM0(); }
        SBAR();
#pragma unroll
        for (int i = 0; i < 4; ++i) {
            aA[i][0] = *(const bf16x8*)(AbN + aOffB + i * 2048 + sw0);
            aA[i][1] = *(const bf16x8*)(AbN + aOffB + i * 2048 + sw1);
        }
#pragma unroll
        for (int j = 0; j < 2; ++j) {
            b0[j][0] = *(const bf16x8*)(BbN + bOffB + j * 2048 + sw0);
            b0[j][1] = *(const bf16x8*)(BbN + bOffB + j * 2048 + sw1);
        }
        LGKM(12); SCHB();
        __builtin_amdgcn_s_setprio(1);
#pragma unroll
        for (int i = 0; i < 4; ++i)
#pragma unroll
            for (int j = 0; j < 2; ++j) {
                acc[4 + i][2 + j] = __builtin_amdgcn_mfma_f32_16x16x32_bf16(aB[i][0], b1[j][0], acc[4 + i][2 + j], 0, 0, 0);
                acc[4 + i][2 + j] = __builtin_amdgcn_mfma_f32_16x16x32_bf16(aB[i][1], b1[j][1], acc[4 + i][2 + j], 0, 0, 0);
            }
        __builtin_amdgcn_s_setprio(0);
        SBAR();
    }

    // C write (verified 16x16x32 C/D layout: col = lane&15, row = (lane>>4)*4 + r)
    const int er = g * 4;
#pragma unroll
    for (int i = 0; i < 8; ++i)
#pragma unroll
        for (int j = 0; j < 4; ++j) {
            int row = m0 + wr * 128 + i * 16 + er;
            int col = n0 + wc * 64 + j * 16 + fr;
#pragma unroll
            for (int r = 0; r < 4; ++r) {
                if (F32OUT)
                    ((float*)Cg)[(size_t)(row + r) * ldc + col] = acc[i][j][r];
                else
                    ((unsigned short*)Cg)[(size_t)(row + r) * ldc + col] = f2b(acc[i][j][r]);
            }
        }
#undef STG_A
#undef STG_B
#undef ST_Aa
#undef ST_Ab
#undef ST_Ba
#undef ST_Bb
#undef VM6
#undef VM0
#undef LGKM
#undef SCHB
#undef SBAR
}

// ---------------------------------------------------------------------------
// Mega GEMM: U[8192 x 12288] = Gt * Xb^T, with XCD supertile swizzle.
// Assumes RR workgroup->XCD dispatch (xcd = bid % 8). Each XCD owns a fixed
// 4-block y-band (its 4 A-panels stay L2-resident) and walks x in 8-wide
// supertiles: concurrent per-XCD set = 4y x 8x -> per-K-tile L2 working set
// ~384 KB instead of ~33 MB.
__global__ __launch_bounds__(512, 2) void k_gemm_mega(
    const unsigned short* __restrict__ Ag, const unsigned short* __restrict__ Bg,
    unsigned short* __restrict__ Cg)
{
    const int bid = blockIdx.x;       // 0..1535
    const int xcd = bid & 7;
    const int t   = bid >> 3;         // 0..191
    const int sx  = t >> 5;           // 0..5
    const int loc = t & 31;
    const int x = sx * 8 + (loc & 7); // 0..47  (N block)
    const int y = xcd * 4 + (loc >> 3); // 0..31 (M block)
    gemm_core<false>(Ag, Bg, (void*)Cg, VV, VV, 0, y * 256, x * 256, NCOL);
}

// ---------------------------------------------------------------------------
// Small GEMM (A_s^2)^T, split-K=2 over both supports: 256 blocks -> full GPU.
// Partials fp32 into P[(s*2+kz)][2048x2048].
__global__ __launch_bounds__(512, 2) void k_gemm_small(
    const unsigned short* __restrict__ Gt, const unsigned short* __restrict__ Abf,
    float* __restrict__ P)
{
    const int bid = blockIdx.x;       // 0..255
    const int s  = bid >> 7;
    const int kz = (bid >> 6) & 1;
    const int y  = (bid >> 3) & 7;
    const int x  = bid & 7;
    const unsigned short* A = Gt + (size_t)(2 * s) * VB;
    const unsigned short* B = Abf + (size_t)s * VB;
    float* C = P + (size_t)(s * 2 + kz) * VB;
    gemm_core<true>(A, B, (void*)C, VV, 1024, kz * 1024, y * 256, x * 256, VV);
}

// ---------------------------------------------------------------------------
// Combine split-K partials: Gt[(2s+1)*VB + i] = bf16(P[2s][i] + P[2s+1][i])
__global__ void k_combine(const float* __restrict__ P,
                          unsigned short* __restrict__ Gt) {
    const int s = blockIdx.y;
    size_t i = ((size_t)blockIdx.x * 256 + threadIdx.x) * 4;
    float4 a = *(const float4*)(P + (size_t)(2 * s) * VB + i);
    float4 b = *(const float4*)(P + (size_t)(2 * s + 1) * VB + i);
    ushort4 o;
    o.x = f2b(a.x + b.x); o.y = f2b(a.y + b.y);
    o.z = f2b(a.z + b.z); o.w = f2b(a.w + b.w);
    *(ushort4*)(Gt + (size_t)(2 * s + 1) * VB + i) = o;
}

// ---------------------------------------------------------------------------
// Epilogue channel mix (fp32):
//   y[b,o,w,l] = bias[o] + sum_c W[o][c]*x[b,c,w,l]
//              + sum_{k,c} W[o][(k+1)*32+c] * U[k*V + w][(b*32+c)*12 + l]
__global__ __launch_bounds__(192) void k_epilogue(const float* __restrict__ x,
                                                  const unsigned short* __restrict__ U,
                                                  const float* __restrict__ W,
                                                  const float* __restrict__ bias,
                                                  float* __restrict__ y) {
    __shared__ float xs[32][192];            // 24 KB
    __shared__ unsigned short us[64][392];   // padded rows (784 B, 16B-mult) ~50 KB
    const int b = blockIdx.y;
    const int w0 = blockIdx.x * 16;
    const int tid = threadIdx.x;  // 0..191

    const float* xp = x + ((size_t)(b * 32) * VV + w0) * LL;
#pragma unroll 4
    for (int c = 0; c < 32; c++)
        xs[c][tid] = xp[(size_t)c * (VV * LL) + tid];

    // U staging: 64 rows x 768 B, b128 chunks, 4 rows x 48 chunks per pass
    {
        const int r0 = tid / 48;          // 0..3
        const int c0 = tid - r0 * 48;     // 0..47
#pragma unroll
        for (int it = 0; it < 16; ++it) {
            int r = it * 4 + r0;          // 0..63
            int krow = (r >> 4) * VV + w0 + (r & 15);
            const unsigned short* up = U + (size_t)krow * NCOL + b * 384 + c0 * 8;
            *(bf16x8*)&us[r][c0 * 8] = *(const bf16x8*)up;
        }
    }
    __syncthreads();

    const int w = tid / 12, l = tid - w * 12;
    float acc[32];
#pragma unroll
    for (int o = 0; o < 32; o++) acc[o] = bias[o];

    for (int c = 0; c < 32; c++) {
        float h = xs[c][tid];
#pragma unroll
        for (int o = 0; o < 32; o++) acc[o] += W[o * 160 + c] * h;
    }
    for (int c = 0; c < 32; c++) {
#pragma unroll
        for (int k = 0; k < 4; k++) {
            float h = b2f(us[k * 16 + w][c * 12 + l]);
#pragma unroll
            for (int o = 0; o < 32; o++) acc[o] += W[o * 160 + (k + 1) * 32 + c] * h;
        }
    }

    float* yp = y + ((size_t)(b * 32) * VV + w0) * LL;
#pragma unroll
    for (int o = 0; o < 32; o++)
        yp[(size_t)o * (VV * LL) + tid] = acc[o];
}

// ---------------------------------------------------------------------------
extern "C" void kernel_launch(void* const* d_in, const int* in_sizes, int n_in,
                              void* d_out, int out_size, void* d_ws, size_t ws_size,
                              hipStream_t stream) {
    const float* x        = (const float*)d_in[0];
    const float* supports = (const float*)d_in[1];
    const float* W        = (const float*)d_in[2];
    const float* bias     = (const float*)d_in[3];
    float* y = (float*)d_out;

    char* ws = (char*)d_ws;
    unsigned short* Xb  = (unsigned short*)(ws);                 // 50,331,648 B
    unsigned short* Gt  = (unsigned short*)(ws + 50331648);      // 33,554,432 B
    unsigned short* Abf = (unsigned short*)(ws + 83886080);      // 16,777,216 B
    unsigned short* U   = (unsigned short*)(ws + 100663296);     // 201,326,592 B
    float*          P   = (float*)(ws + 100663296);              // 67 MB scratch (reuses U area)

    // 1. supports -> Abf (bf16 natural) + Gt blocks 0,2 (transposed), fused
    k_prepA<<<dim3(64, 64, 2), 256, 0, stream>>>(supports, Abf, Gt);

    // 2. (A_s^2)^T split-K=2 partials (both supports, 256 blocks = full GPU)
    k_gemm_small<<<dim3(256), 512, 0, stream>>>(Gt, Abf, P);

    // 3. combine partials -> Gt blocks 1 and 3
    k_combine<<<dim3(4096, 2), 256, 0, stream>>>(P, Gt);

    // 4. x -> Xb (transposed bf16)
    k_transpose_x<<<dim3(16, 1024), 256, 0, stream>>>(x, Xb);

    // 5. mega GEMM with XCD supertile swizzle (overwrites P area with U)
    k_gemm_mega<<<dim3(1536), 512, 0, stream>>>(Gt, Xb, U);

    // 6. epilogue channel mix -> y
    k_epilogue<<<dim3(VV / 16, BB), 192, 0, stream>>>(x, U, W, bias, y);
}

// Round 8
// 741.179 us; speedup vs baseline: 1.4926x; 1.1248x over previous
//
#include <hip/hip_runtime.h>

// Problem constants
#define BB 32
#define CC 32
#define VV 2048
#define LL 12
#define NCOL 12288      // B*C*L columns of the mega GEMM
#define MMEGA 8192      // 4*V rows (k-blocks: A0, A0^2, A1, A1^2)
#define VB ((size_t)VV * VV)
#define PPB 24576       // positions per batch: V*L

typedef __attribute__((ext_vector_type(8))) short bf16x8;
typedef __attribute__((ext_vector_type(4))) float f32x4;

__device__ __forceinline__ unsigned short f2b(float f) {
    union { float f; unsigned u; } v; v.f = f;
    unsigned u = v.u;
    unsigned r = (u + 0x7fffu + ((u >> 16) & 1u)) >> 16;
    return (unsigned short)r;
}
__device__ __forceinline__ float bits2f(unsigned u) {
    union { unsigned u; float f; } v; v.u = u;
    return v.f;
}

__device__ __forceinline__ void stg(const unsigned short* g, unsigned short* l) {
    __builtin_amdgcn_global_load_lds((const __attribute__((address_space(1))) void*)g,
                                     (__attribute__((address_space(3))) void*)l, 16, 0, 0);
}

// ---------------------------------------------------------------------------
// Kernel 1: merged convert + transpose of supports.
//   Abf[s][v][w] = bf16(A_s[v][w]);  Gt[(2s)*V + w][v] = bf16(A_s[v][w])
__global__ void k_prepA(const float* __restrict__ A,
                        unsigned short* __restrict__ Abf,
                        unsigned short* __restrict__ Gt) {
    __shared__ float t[32][33];
    const int s = blockIdx.z;
    const float* As = A + (size_t)s * VB;
    const int w0 = blockIdx.x * 32, v0 = blockIdx.y * 32;
    const int tid = threadIdx.x;
    const int cc = tid & 31;
    unsigned short* Ao = Abf + (size_t)s * VB;
#pragma unroll
    for (int i = 0; i < 4; i++) {
        int rr = (tid >> 5) + i * 8;
        float val = As[(size_t)(v0 + rr) * VV + w0 + cc];
        t[rr][cc] = val;
        Ao[(size_t)(v0 + rr) * VV + w0 + cc] = f2b(val);
    }
    __syncthreads();
    unsigned short* G = Gt + (size_t)(2 * s) * VB;
#pragma unroll
    for (int i = 0; i < 4; i++) {
        int rr = (tid >> 5) + i * 8;
        G[(size_t)(w0 + rr) * VV + v0 + cc] = f2b(t[cc][rr]);
    }
}

// ---------------------------------------------------------------------------
// Kernel 2: transpose x [B][C][V][L] fp32 -> Xb [(b*32+c)*12 + l][v] bf16
__global__ void k_transpose_x(const float* __restrict__ x,
                              unsigned short* __restrict__ Xb) {
    __shared__ float t[128 * 13];
    const int bc = blockIdx.y;
    const int v0 = blockIdx.x * 128;
    const float* xs = x + (size_t)bc * VV * LL + (size_t)v0 * LL;
    const int tid = threadIdx.x;  // 256
#pragma unroll
    for (int i = 0; i < 6; i++) {
        int e = tid + i * 256;            // 0..1535 = col*12+row
        int col = e / 12, row = e - col * 12;
        t[col * 13 + row] = xs[e];
    }
    __syncthreads();
    unsigned short* X = Xb + (size_t)bc * LL * VV + v0;
#pragma unroll
    for (int i = 0; i < 2; i++) {
        int flat = tid + i * 256;         // 384 ushort4 chunks: 12 rows x 32
        if (flat < 384) {
            int row = flat >> 5;
            int col = (flat & 31) * 4;
            ushort4 o;
            o.x = f2b(t[(col + 0) * 13 + row]);
            o.y = f2b(t[(col + 1) * 13 + row]);
            o.z = f2b(t[(col + 2) * 13 + row]);
            o.w = f2b(t[(col + 3) * 13 + row]);
            *(ushort4*)&X[(size_t)row * VV + col] = o;
        }
    }
}

// ---------------------------------------------------------------------------
// Core: 256x256-tile 8-phase bf16 MFMA GEMM (T2+T3+T4+T5), one-phase-ahead
// register fragment pipeline, counted vmcnt(6)/lgkmcnt.
//   C[m,n] = sum_{k in [koff, koff+Kloc)} Aop[m0+m, k] * Bop[n0+n, k]
// OMODE: 0 = bf16 row-major (ldc), 1 = fp32 row-major (split-K partials),
//        2 = U-prime scatter: U'[(col/12)*4 + row/2048][(row%2048)*12 + col%12]
template<int OMODE>
__device__ __forceinline__ void gemm_core(const unsigned short* __restrict__ Ag,
                                          const unsigned short* __restrict__ Bg,
                                          void* __restrict__ Cg,
                                          int ld, int Kloc, int koff,
                                          int m0, int n0, int ldc)
{
    __shared__ unsigned short SH[65536];   // 128 KiB: [buf][A 16K | B 16K] elems
    const int tid  = threadIdx.x;
    const int lane = tid & 63;
    const int wid  = tid >> 6;
    const int wr   = wid >> 2;          // 0..1  (M strip of 128 rows)
    const int wc   = wid & 3;           // 0..3  (N strip of 64 rows)
    const int fr   = lane & 15;
    const int g    = lane >> 4;         // 0..3
    const int NT   = Kloc >> 6;

    const unsigned short* gA = Ag + (size_t)m0 * ld + koff;
    const unsigned short* gB = Bg + (size_t)n0 * ld + koff;

    // --- staging lane constants (pre-swizzled global source) ---
    const int lrow  = lane >> 3;            // row within 8-row unit
    const int lslot = (lane & 7) ^ lrow;    // XOR-swizzled 16B k-slot
    const size_t laneGOff = (size_t)lrow * ld + lslot * 8;

    // unit base rows (2 units of 8 rows per wave per half-tile)
    const int qa  = wid * 16;
    const int rA0 = (qa & 63) + ((qa & 64) << 1);              // A-alpha rows
    const int rA1 = ((qa + 8) & 63) + (((qa + 8) & 64) << 1);
    const int rB0 = (qa & 31) + ((qa & ~31) << 1);             // B-alpha rows
    const int rB1 = ((qa + 8) & 31) + (((qa + 8) & ~31) << 1);

    // --- read-side lane constants (byte offsets, swizzled slots) ---
    const int frlow = fr & 7;
    const int sw0 = ((0 + g) ^ frlow) << 4;   // k-step 0
    const int sw1 = ((4 + g) ^ frlow) << 4;   // k-step 1
    const int aOffB = (wr * 128 + fr) * 128;  // bytes within A tile
    const int bOffB = (wc * 64  + fr) * 128;  // bytes within B tile

    f32x4 acc[8][4];
#pragma unroll
    for (int i = 0; i < 8; ++i)
#pragma unroll
        for (int j = 0; j < 4; ++j) { f32x4 z = {0.f, 0.f, 0.f, 0.f}; acc[i][j] = z; }

#define STG_A(Lb, rb, kt) stg(gA + (size_t)(rb) * ld + ((size_t)(kt) << 6) + laneGOff, (Lb) + (rb) * 64)
#define STG_B(Lb, rb, kt) stg(gB + (size_t)(rb) * ld + ((size_t)(kt) << 6) + laneGOff, (Lb) + (rb) * 64)
#define ST_Aa(Lb, kt) do { if ((kt) < NT) { STG_A(Lb, rA0, kt);      STG_A(Lb, rA1, kt);      } } while (0)
#define ST_Ab(Lb, kt) do { if ((kt) < NT) { STG_A(Lb, rA0 + 64, kt); STG_A(Lb, rA1 + 64, kt); } } while (0)
#define ST_Ba(Lb, kt) do { if ((kt) < NT) { STG_B(Lb, rB0, kt);      STG_B(Lb, rB1, kt);      } } while (0)
#define ST_Bb(Lb, kt) do { if ((kt) < NT) { STG_B(Lb, rB0 + 32, kt); STG_B(Lb, rB1 + 32, kt); } } while (0)
#define VM6() asm volatile("s_waitcnt vmcnt(6)" ::: "memory")
#define VM0() asm volatile("s_waitcnt vmcnt(0)" ::: "memory")
#define LGKM(n) asm volatile("s_waitcnt lgkmcnt(" #n ")" ::: "memory")
#define SCHB() __builtin_amdgcn_sched_barrier(0)
#define SBAR() __builtin_amdgcn_s_barrier()

    unsigned short* A0L = SH;
    unsigned short* B0L = SH + 16384;
    unsigned short* A1L = SH + 32768;
    unsigned short* B1L = SH + 49152;

    // Prologue: stage 7 half-tile units; vmcnt(6) -> all of tile 0 landed.
    ST_Aa(A0L, 0); ST_Ab(A0L, 0); ST_Ba(B0L, 0); ST_Bb(B0L, 0);
    ST_Aa(A1L, 1); ST_Ab(A1L, 1); ST_Ba(B1L, 1);
    if (NT > 1) { VM6(); } else { VM0(); }
    SBAR();

    // Fragment register sets (one-phase-ahead pipeline)
    bf16x8 aA[4][2], aB[4][2], b0[2][2], b1[2][2];
    {
        const char* Ab = (const char*)SH;
        const char* Bb = Ab + 32768;
#pragma unroll
        for (int i = 0; i < 4; ++i) {
            aA[i][0] = *(const bf16x8*)(Ab + aOffB + i * 2048 + sw0);
            aA[i][1] = *(const bf16x8*)(Ab + aOffB + i * 2048 + sw1);
        }
#pragma unroll
        for (int j = 0; j < 2; ++j) {
            b0[j][0] = *(const bf16x8*)(Bb + bOffB + j * 2048 + sw0);
            b0[j][1] = *(const bf16x8*)(Bb + bOffB + j * 2048 + sw1);
        }
    }

    for (int t = 0; t < NT; ++t) {
        const char* Ab  = (const char*)(SH + ((t & 1) << 15));
        const char* Bb  = Ab + 32768;
        const char* AbN = (const char*)(SH + (((t + 1) & 1) << 15));
        const char* BbN = AbN + 32768;
        unsigned short* An = SH + (((t + 1) & 1) << 15);
        unsigned short* Bn = An + 16384;
        unsigned short* Ac = SH + ((t & 1) << 15);
        unsigned short* Bc = Ac + 16384;
        (void)An;

        // ---- P1: read aB(t); stage B-beta(t+1); MFMA Q(M0,N0) w/ aA,b0 ----
#pragma unroll
        for (int i = 0; i < 4; ++i) {
            aB[i][0] = *(const bf16x8*)(Ab + aOffB + 8192 + i * 2048 + sw0);
            aB[i][1] = *(const bf16x8*)(Ab + aOffB + 8192 + i * 2048 + sw1);
        }
        ST_Bb(Bn, t + 1);
        SBAR(); LGKM(8); SCHB();
        __builtin_amdgcn_s_setprio(1);
#pragma unroll
        for (int i = 0; i < 4; ++i)
#pragma unroll
            for (int j = 0; j < 2; ++j) {
                acc[i][j] = __builtin_amdgcn_mfma_f32_16x16x32_bf16(aA[i][0], b0[j][0], acc[i][j], 0, 0, 0);
                acc[i][j] = __builtin_amdgcn_mfma_f32_16x16x32_bf16(aA[i][1], b0[j][1], acc[i][j], 0, 0, 0);
            }
        __builtin_amdgcn_s_setprio(0);
        SBAR();

        // ---- P2: read b1(t); stage A-alpha(t+2); MFMA Q(M1,N0) w/ aB,b0 ----
#pragma unroll
        for (int j = 0; j < 2; ++j) {
            b1[j][0] = *(const bf16x8*)(Bb + bOffB + 4096 + j * 2048 + sw0);
            b1[j][1] = *(const bf16x8*)(Bb + bOffB + 4096 + j * 2048 + sw1);
        }
        ST_Aa(Ac, t + 2);
        SBAR(); LGKM(4); SCHB();
        __builtin_amdgcn_s_setprio(1);
#pragma unroll
        for (int i = 0; i < 4; ++i)
#pragma unroll
            for (int j = 0; j < 2; ++j) {
                acc[4 + i][j] = __builtin_amdgcn_mfma_f32_16x16x32_bf16(aB[i][0], b0[j][0], acc[4 + i][j], 0, 0, 0);
                acc[4 + i][j] = __builtin_amdgcn_mfma_f32_16x16x32_bf16(aB[i][1], b0[j][1], acc[4 + i][j], 0, 0, 0);
            }
        __builtin_amdgcn_s_setprio(0);
        SBAR();

        // ---- P3: stage A-beta(t+2); MFMA Q(M0,N1) w/ aA,b1 ----
        ST_Ab(Ac, t + 2);
        SBAR(); LGKM(0); SCHB();
        __builtin_amdgcn_s_setprio(1);
#pragma unroll
        for (int i = 0; i < 4; ++i)
#pragma unroll
            for (int j = 0; j < 2; ++j) {
                acc[i][2 + j] = __builtin_amdgcn_mfma_f32_16x16x32_bf16(aA[i][0], b1[j][0], acc[i][2 + j], 0, 0, 0);
                acc[i][2 + j] = __builtin_amdgcn_mfma_f32_16x16x32_bf16(aA[i][1], b1[j][1], acc[i][2 + j], 0, 0, 0);
            }
        __builtin_amdgcn_s_setprio(0);
        SBAR();

        // ---- P4: stage B-alpha(t+2); counted vmcnt; read aA,b0(t+1) ----
        ST_Ba(Bc, t + 2);
        if (t + 2 < NT) { VM6(); } else { VM0(); }
        SBAR();
#pragma unroll
        for (int i = 0; i < 4; ++i) {
            aA[i][0] = *(const bf16x8*)(AbN + aOffB + i * 2048 + sw0);
            aA[i][1] = *(const bf16x8*)(AbN + aOffB + i * 2048 + sw1);
        }
#pragma unroll
        for (int j = 0; j < 2; ++j) {
            b0[j][0] = *(const bf16x8*)(BbN + bOffB + j * 2048 + sw0);
            b0[j][1] = *(const bf16x8*)(BbN + bOffB + j * 2048 + sw1);
        }
        LGKM(12); SCHB();
        __builtin_amdgcn_s_setprio(1);
#pragma unroll
        for (int i = 0; i < 4; ++i)
#pragma unroll
            for (int j = 0; j < 2; ++j) {
                acc[4 + i][2 + j] = __builtin_amdgcn_mfma_f32_16x16x32_bf16(aB[i][0], b1[j][0], acc[4 + i][2 + j], 0, 0, 0);
                acc[4 + i][2 + j] = __builtin_amdgcn_mfma_f32_16x16x32_bf16(aB[i][1], b1[j][1], acc[4 + i][2 + j], 0, 0, 0);
            }
        __builtin_amdgcn_s_setprio(0);
        SBAR();
    }

    // C write (verified 16x16x32 C/D layout: col = lane&15, row = (lane>>4)*4 + r)
    const int er = g * 4;
    if (OMODE == 2) {
        int bcj[4], lj[4];
#pragma unroll
        for (int j = 0; j < 4; ++j) {
            int col = n0 + wc * 64 + j * 16 + fr;
            bcj[j] = col / 12;
            lj[j]  = col - bcj[j] * 12;
        }
#pragma unroll
        for (int i = 0; i < 8; ++i) {
            int rowm = m0 + wr * 128 + i * 16 + er;
            int kb = rowm >> 11, w = rowm & 2047;
#pragma unroll
            for (int j = 0; j < 4; ++j) {
                size_t base = ((size_t)bcj[j] * 4 + kb) * PPB + (size_t)w * 12 + lj[j];
#pragma unroll
                for (int r = 0; r < 4; ++r)
                    ((unsigned short*)Cg)[base + (size_t)r * 12] = f2b(acc[i][j][r]);
            }
        }
    } else {
#pragma unroll
        for (int i = 0; i < 8; ++i)
#pragma unroll
            for (int j = 0; j < 4; ++j) {
                int row = m0 + wr * 128 + i * 16 + er;
                int col = n0 + wc * 64 + j * 16 + fr;
#pragma unroll
                for (int r = 0; r < 4; ++r) {
                    if (OMODE == 1)
                        ((float*)Cg)[(size_t)(row + r) * ldc + col] = acc[i][j][r];
                    else
                        ((unsigned short*)Cg)[(size_t)(row + r) * ldc + col] = f2b(acc[i][j][r]);
                }
            }
    }
#undef STG_A
#undef STG_B
#undef ST_Aa
#undef ST_Ab
#undef ST_Ba
#undef ST_Bb
#undef VM6
#undef VM0
#undef LGKM
#undef SCHB
#undef SBAR
}

// ---------------------------------------------------------------------------
// Mega GEMM: U'[bc*4+k][w*12+l] = Gt * Xb^T, XCD supertile swizzle.
__global__ __launch_bounds__(512, 2) void k_gemm_mega(
    const unsigned short* __restrict__ Ag, const unsigned short* __restrict__ Bg,
    unsigned short* __restrict__ Cg)
{
    const int bid = blockIdx.x;       // 0..1535
    const int xcd = bid & 7;
    const int t   = bid >> 3;         // 0..191
    const int sx  = t >> 5;           // 0..5
    const int loc = t & 31;
    const int x = sx * 8 + (loc & 7);   // 0..47  (N block)
    const int y = xcd * 4 + (loc >> 3); // 0..31 (M block)
    gemm_core<2>(Ag, Bg, (void*)Cg, VV, VV, 0, y * 256, x * 256, 0);
}

// ---------------------------------------------------------------------------
// Small GEMM (A_s^2)^T, split-K=2 over both supports: 256 blocks.
__global__ __launch_bounds__(512, 2) void k_gemm_small(
    const unsigned short* __restrict__ Gt, const unsigned short* __restrict__ Abf,
    float* __restrict__ P)
{
    const int bid = blockIdx.x;       // 0..255
    const int s  = bid >> 7;
    const int kz = (bid >> 6) & 1;
    const int y  = (bid >> 3) & 7;
    const int x  = bid & 7;
    const unsigned short* A = Gt + (size_t)(2 * s) * VB;
    const unsigned short* B = Abf + (size_t)s * VB;
    float* C = P + (size_t)(s * 2 + kz) * VB;
    gemm_core<1>(A, B, (void*)C, VV, 1024, kz * 1024, y * 256, x * 256, VV);
}

// ---------------------------------------------------------------------------
// Combine split-K partials: Gt[(2s+1)*VB + i] = bf16(P[2s][i] + P[2s+1][i])
__global__ void k_combine(const float* __restrict__ P,
                          unsigned short* __restrict__ Gt) {
    const int s = blockIdx.y;
    size_t i = ((size_t)blockIdx.x * 256 + threadIdx.x) * 4;
    float4 a = *(const float4*)(P + (size_t)(2 * s) * VB + i);
    float4 b = *(const float4*)(P + (size_t)(2 * s + 1) * VB + i);
    ushort4 o;
    o.x = f2b(a.x + b.x); o.y = f2b(a.y + b.y);
    o.z = f2b(a.z + b.z); o.w = f2b(a.w + b.w);
    *(ushort4*)(Gt + (size_t)(2 * s + 1) * VB + i) = o;
}

// ---------------------------------------------------------------------------
// Epilogue v2: pure streaming channel mix, no LDS.
//   y[b,o,p] = bias[o] + sum_c W[o][c]*x[b,c,p]
//            + sum_{k,c} W[o][(k+1)*32+c] * U'[(b*32+c)*4+k][p]
// Each thread owns 2 consecutive positions p; all loads/stores coalesced.
__global__ __launch_bounds__(256) void k_epilogue2(const float* __restrict__ x,
                                                   const unsigned short* __restrict__ Up,
                                                   const float* __restrict__ W,
                                                   const float* __restrict__ bias,
                                                   float* __restrict__ y) {
    const int gid = blockIdx.x * 256 + threadIdx.x;
    const int p0 = gid * 2;
    const int b = p0 / PPB;             // uniform per block (PPB % 512 == 0)
    const int pl = p0 - b * PPB;
    const float* xp = x + ((size_t)b * 32) * PPB + pl;
    const unsigned short* up = Up + ((size_t)b * 128) * PPB + pl;

    float a0[32], a1[32];
#pragma unroll
    for (int o = 0; o < 32; ++o) { float bv = bias[o]; a0[o] = bv; a1[o] = bv; }

    // identity block (fp32)
#pragma unroll 4
    for (int c = 0; c < 32; ++c) {
        float2 xv = *(const float2*)(xp + (size_t)c * PPB);
#pragma unroll
        for (int o = 0; o < 32; ++o) {
            float wv = W[o * 160 + c];
            a0[o] += wv * xv.x; a1[o] += wv * xv.y;
        }
    }
    // graph-conv blocks
#pragma unroll
    for (int k = 0; k < 4; ++k) {
#pragma unroll 4
        for (int c = 0; c < 32; ++c) {
            unsigned uv = *(const unsigned*)(up + (size_t)(c * 4 + k) * PPB);
            float u0 = bits2f(uv << 16);
            float u1 = bits2f(uv & 0xffff0000u);
#pragma unroll
            for (int o = 0; o < 32; ++o) {
                float wv = W[o * 160 + (k + 1) * 32 + c];
                a0[o] += wv * u0; a1[o] += wv * u1;
            }
        }
    }

    float* yp = y + ((size_t)b * 32) * PPB + pl;
#pragma unroll
    for (int o = 0; o < 32; ++o) {
        float2 ov; ov.x = a0[o]; ov.y = a1[o];
        *(float2*)(yp + (size_t)o * PPB) = ov;
    }
}

// ---------------------------------------------------------------------------
extern "C" void kernel_launch(void* const* d_in, const int* in_sizes, int n_in,
                              void* d_out, int out_size, void* d_ws, size_t ws_size,
                              hipStream_t stream) {
    const float* x        = (const float*)d_in[0];
    const float* supports = (const float*)d_in[1];
    const float* W        = (const float*)d_in[2];
    const float* bias     = (const float*)d_in[3];
    float* y = (float*)d_out;

    char* ws = (char*)d_ws;
    unsigned short* Xb  = (unsigned short*)(ws);                 // 50,331,648 B
    unsigned short* Gt  = (unsigned short*)(ws + 50331648);      // 33,554,432 B
    unsigned short* Abf = (unsigned short*)(ws + 83886080);      // 16,777,216 B
    unsigned short* Up  = (unsigned short*)(ws + 100663296);     // 201,326,592 B
    float*          P   = (float*)(ws + 100663296);              // 67 MB scratch (reused by Up)

    // 1. supports -> Abf (bf16 natural) + Gt blocks 0,2 (transposed), fused
    k_prepA<<<dim3(64, 64, 2), 256, 0, stream>>>(supports, Abf, Gt);

    // 2. (A_s^2)^T split-K=2 partials (both supports, 256 blocks)
    k_gemm_small<<<dim3(256), 512, 0, stream>>>(Gt, Abf, P);

    // 3. combine partials -> Gt blocks 1 and 3
    k_combine<<<dim3(4096, 2), 256, 0, stream>>>(P, Gt);

    // 4. x -> Xb (transposed bf16)
    k_transpose_x<<<dim3(16, 1024), 256, 0, stream>>>(x, Xb);

    // 5. mega GEMM, writes epilogue-native U' layout (overwrites P area)
    k_gemm_mega<<<dim3(1536), 512, 0, stream>>>(Gt, Xb, Up);

    // 6. streaming epilogue channel mix -> y
    k_epilogue2<<<dim3(786432 / 512), 256, 0, stream>>>(x, Up, W, bias, y);
}